// Round 13
// baseline (2538.824 us; speedup 1.0000x reference)
//
#include <hip/hip_runtime.h>
#include <hip/hip_bf16.h>
#include <math.h>

typedef __bf16 bf16;
typedef bf16 bf16x8 __attribute__((ext_vector_type(8)));
typedef bf16 bf16x4 __attribute__((ext_vector_type(4)));
typedef float f32x4 __attribute__((ext_vector_type(4)));

#define BQ 32
#define TT 197
#define DD 768
#define HH 12
#define FF 3072
#define LL 12
#define TP 224
#define MR 6304   // B*T
#define MP 6400   // padded to 50*128
#define KST 72    // K LDS row stride (elements)
#define PST 232   // Vt LDS row stride (elements)
#define PST2 136  // P half-buffer row stride (elements)
#define NSPLIT 2  // MLP2 split-K factor

typedef __attribute__((address_space(1))) const void gv_t;
typedef __attribute__((address_space(3))) void lv_t;

__device__ __forceinline__ void gld16(const void* g, void* l) {
    __builtin_amdgcn_global_load_lds((gv_t*)g, (lv_t*)l, 16, 0, 0);
}

__device__ __forceinline__ f32x4 mfma16(bf16x8 a, bf16x8 b, f32x4 c) {
    return __builtin_amdgcn_mfma_f32_16x16x32_bf16(a, b, c, 0, 0, 0);
}

// tanh-approx GELU via hw v_exp_f32; overflow-safe (e=inf -> th=1)
__device__ __forceinline__ float fast_gelu(float v) {
    float t = 0.79788456080286535588f * v * (1.0f + 0.044715f * v * v);
    float e = __expf(2.0f * t);
    float th = 1.0f - 2.0f / (e + 1.0f);
    return 0.5f * v * (1.0f + th);
}

// bijective XCD swizzle (m204): consecutive wgid stay on one XCD
__device__ __forceinline__ int xcd_swz(int bid, int nwg) {
    int q = nwg >> 3, r = nwg & 7;
    int xcd = bid & 7, pos = bid >> 3;
    int base = (xcd < r) ? xcd * (q + 1) : r * (q + 1) + (xcd - r) * q;
    return base + pos;
}

// ---------------------------------------------------------------------------
// C = A(M,K) @ W(N,K)^T GEMM, 128x128 tile, BK=64, 4 waves, single-buffered
// (m97 structure; r5-proven). Compile-time K/N/geometry; full K-loop unroll.
// A-side: gld16 with source-side XOR swizzle (LDS dest linear, rule #21).
// B-side: WF32=0 -> same gld16 path (bf16 W); WF32=1 -> fp32 W loaded to
// regs (2x float4/lane), cvt to bf16 (same RNE as cast kernel -> bit-identical)
// and ds_write_b128 to the SWIZZLED LDS slot (write-side swizzle; reads
// unchanged, 0 bank conflicts). Removes the 339 MB/iteration weight precast.
// EPI 0: +bias, patch-embed; EPI 1: +bias, GELU->bf16; EPI 2: +bias,
// residual +=; EPI 3: raw partial write (bf16, stride DD).
// ---------------------------------------------------------------------------
template <int EPI, int SPLITK, int KTOT, int NN, int GX, int GY, int WF32>
__global__ __launch_bounds__(256, 4)
void gemm_bt(const bf16* __restrict__ A, const void* __restrict__ Wv,
             const float* __restrict__ bias,
             float* __restrict__ outF, bf16* __restrict__ outB,
             const float* __restrict__ pos) {
    __shared__ bf16 As[128 * 64];
    __shared__ bf16 Bs[128 * 64];
    const int tid = threadIdx.x;
    const int lane = tid & 63, wave = tid >> 6;
    const int wm = wave >> 1, wn = wave & 1;

    const int wgid = xcd_swz(blockIdx.x, GX * GY * SPLITK);
    const int ks   = (SPLITK > 1) ? wgid / (GX * GY) : 0;
    const int rem  = (SPLITK > 1) ? wgid % (GX * GY) : wgid;
    const int bx = rem % GX, by = rem / GX;
    const int m0 = by * 128, n0 = bx * 128;

    constexpr int kb = KTOT / SPLITK;
    constexpr int nt = kb / 64;
    const int k0 = ks * kb;

    f32x4 acc[4][4] = {};
    const bf16* Ab = A + (size_t)m0 * KTOT;
    const bf16*  Wb16 = (const bf16*)Wv + (size_t)n0 * KTOT;
    const float* Wf32 = (const float*)Wv + (size_t)n0 * KTOT;

#pragma unroll
    for (int t = 0; t < nt; ++t) {
        const int kt = k0 + t * 64;
#pragma unroll
        for (int i = 0; i < 4; i++) {
            int idx = i * 256 + tid;
            int row = idx >> 3, cb = idx & 7;
            int gcb = cb ^ (row & 7);   // pre-swizzled source column-block
            gld16(Ab + (size_t)row * KTOT + kt + gcb * 8, As + idx * 8);
            if (!WF32)
                gld16(Wb16 + (size_t)row * KTOT + kt + gcb * 8, Bs + idx * 8);
        }
        if (WF32) {
#pragma unroll
            for (int i = 0; i < 4; i++) {
                int idx = i * 256 + tid;
                int row = idx >> 3, c8 = idx & 7;
                const float* ws = Wf32 + (size_t)row * KTOT + kt + c8 * 8;
                float4 v0 = *(const float4*)ws;
                float4 v1 = *(const float4*)(ws + 4);
                bf16x8 o;
                o[0] = (bf16)v0.x; o[1] = (bf16)v0.y; o[2] = (bf16)v0.z; o[3] = (bf16)v0.w;
                o[4] = (bf16)v1.x; o[5] = (bf16)v1.y; o[6] = (bf16)v1.z; o[7] = (bf16)v1.w;
                *(bf16x8*)(Bs + row * 64 + ((c8 ^ (row & 7)) * 8)) = o;
            }
        }
        __syncthreads();   // drains A gld16 (vmcnt) + B ds_writes (lgkm)
        bf16x8 af[4][2], bfr[4][2];
        const int ca = lane >> 4;
#pragma unroll
        for (int f = 0; f < 4; f++) {
            int rowa = wm * 64 + f * 16 + (lane & 15);
            int ma = rowa & 7;
            af[f][0] = *(const bf16x8*)(As + rowa * 64 + ((ca    ) ^ ma) * 8);
            af[f][1] = *(const bf16x8*)(As + rowa * 64 + ((ca + 4) ^ ma) * 8);
            int rowb = wn * 64 + f * 16 + (lane & 15);
            int mb = rowb & 7;
            bfr[f][0] = *(const bf16x8*)(Bs + rowb * 64 + ((ca    ) ^ mb) * 8);
            bfr[f][1] = *(const bf16x8*)(Bs + rowb * 64 + ((ca + 4) ^ mb) * 8);
        }
#pragma unroll
        for (int kh = 0; kh < 2; kh++)
#pragma unroll
            for (int mf = 0; mf < 4; mf++)
#pragma unroll
                for (int nf = 0; nf < 4; nf++)
                    acc[mf][nf] = mfma16(af[mf][kh], bfr[nf][kh], acc[mf][nf]);
        __syncthreads();
    }

    const int r0 = m0 + wm * 64, c0 = n0 + wn * 64;
#pragma unroll
    for (int mf = 0; mf < 4; mf++) {
#pragma unroll
        for (int j = 0; j < 4; j++) {
            int row = r0 + mf * 16 + ((lane >> 4) * 4) + j;
            int pb = 0, pn = 0;
            if (EPI == 0) { pb = row / 196; pn = row - pb * 196; }
#pragma unroll
            for (int nf = 0; nf < 4; nf++) {
                int col = c0 + nf * 16 + (lane & 15);
                float v = acc[mf][nf][j];
                if (EPI == 0) {
                    v += bias[col];
                    float pv = pos[(size_t)(1 + pn) * DD + col];
                    outF[(size_t)(pb * TT + 1 + pn) * DD + col] = v + pv;
                } else if (EPI == 1) {
                    v += bias[col];
                    outB[(size_t)row * NN + col] = (bf16)fast_gelu(v);
                } else if (EPI == 2) {
                    v += bias[col];
                    if (row < MR) outF[(size_t)row * DD + col] += v;
                } else {
                    outB[(size_t)(ks * MP + row) * DD + col] = (bf16)v;
                }
            }
        }
    }
}

// ---------------------------------------------------------------------------
// Fused LN1 + QKV. Grid 394 blocks x 16 bt-rows. Phase 1: (optional) bf16
// partial reduce + b2 + residual -> h, LN -> swizzled 192x64 bf16 A-tile in
// LDS. Phase 2: (192x192x64) MFMA vs qkv_w, scatter to Q/K/V (B*H, 224, 64).
// W staged via gld16 BEFORE phase 1 (latency hidden).
// ---------------------------------------------------------------------------
template <int ACC>
__global__ __launch_bounds__(256, 2)
void lnqkv_kernel(float* __restrict__ h, const bf16* __restrict__ part,
                  const float* __restrict__ b2p,
                  const float* __restrict__ g, const float* __restrict__ bt,
                  const bf16* __restrict__ qw, const float* __restrict__ qb,
                  bf16* __restrict__ Q, bf16* __restrict__ Kb,
                  bf16* __restrict__ Vb) {
    __shared__ bf16 Asm[192 * 64];
    __shared__ bf16 Wsm[192 * 64];
    const int tid = threadIdx.x, lane = tid & 63, wave = tid >> 6;
    const int g0 = blockIdx.x * 16;

    // stage W early; drains at the __syncthreads below
#pragma unroll
    for (int i = 0; i < 6; i++) {
        int idx = i * 256 + tid;
        int row = idx >> 3, cb = idx & 7;
        int gcb = cb ^ (row & 7);
        gld16(qw + (size_t)row * 64 + gcb * 8, Wsm + idx * 8);
    }

    // phase 1: 4 rows per wave; residual+LN -> Asm (swizzled col-blocks)
    for (int r = 0; r < 4; r++) {
        const int row = g0 + wave * 4 + r;
        float* x = h + (size_t)row * DD;
        float4 a[3];
#pragma unroll
        for (int i = 0; i < 3; i++) a[i] = ((const float4*)x)[lane + i * 64];
        if (ACC) {
#pragma unroll
            for (int s = 0; s < NSPLIT; s++) {
                const bf16x4* ps = (const bf16x4*)(part + ((size_t)s * MP + row) * DD);
#pragma unroll
                for (int i = 0; i < 3; i++) {
                    bf16x4 p = ps[lane + i * 64];
                    a[i].x += (float)p[0]; a[i].y += (float)p[1];
                    a[i].z += (float)p[2]; a[i].w += (float)p[3];
                }
            }
#pragma unroll
            for (int i = 0; i < 3; i++) {
                float4 bb = ((const float4*)b2p)[lane + i * 64];
                a[i].x += bb.x; a[i].y += bb.y; a[i].z += bb.z; a[i].w += bb.w;
                ((float4*)x)[lane + i * 64] = a[i];
            }
        }
        float sum = 0.0f;
#pragma unroll
        for (int i = 0; i < 3; i++) sum += a[i].x + a[i].y + a[i].z + a[i].w;
#pragma unroll
        for (int dd = 1; dd < 64; dd <<= 1) sum += __shfl_xor(sum, dd);
        const float mu = sum * (1.0f / 768.0f);
        float sq = 0.0f;
#pragma unroll
        for (int i = 0; i < 3; i++) {
            float dx = a[i].x - mu, dy = a[i].y - mu, dz = a[i].z - mu, dw = a[i].w - mu;
            sq += dx * dx + dy * dy + dz * dz + dw * dw;
        }
#pragma unroll
        for (int dd = 1; dd < 64; dd <<= 1) sq += __shfl_xor(sq, dd);
        const float is = rsqrtf(sq * (1.0f / 768.0f) + 1e-5f);
#pragma unroll
        for (int i = 0; i < 3; i++) {
            int c4 = lane + i * 64;
            float4 gg = ((const float4*)g)[c4];
            float4 bb = ((const float4*)bt)[c4];
            bf16x4 o;
            o[0] = (bf16)((a[i].x - mu) * is * gg.x + bb.x);
            o[1] = (bf16)((a[i].y - mu) * is * gg.y + bb.y);
            o[2] = (bf16)((a[i].z - mu) * is * gg.z + bb.z);
            o[3] = (bf16)((a[i].w - mu) * is * gg.w + bb.w);
            int col = c4 * 4;
            int arow = (row - g0) * 12 + (col >> 6);
            int acol = col & 63;
            int scol = (((acol >> 3) ^ (arow & 7)) << 3) + (acol & 7);
            *(bf16x4*)(Asm + arow * 64 + scol) = o;
        }
    }
    __syncthreads();   // drains W gld16 (vmcnt) + Asm writes (lgkm)

    // phase 2: QKV MFMA, 3 m-frags x 12 n-frags per wave
    const int ca = lane >> 4;
    bf16x8 af[3][2];
#pragma unroll
    for (int mf = 0; mf < 3; mf++) {
        int row = wave * 48 + mf * 16 + (lane & 15);
        int m7 = row & 7;
        af[mf][0] = *(const bf16x8*)(Asm + row * 64 + ((ca    ) ^ m7) * 8);
        af[mf][1] = *(const bf16x8*)(Asm + row * 64 + ((ca + 4) ^ m7) * 8);
    }
    f32x4 acc[3][12] = {};
#pragma unroll
    for (int nf = 0; nf < 12; nf++) {
        int row = nf * 16 + (lane & 15);
        int m7 = row & 7;
        bf16x8 b0 = *(const bf16x8*)(Wsm + row * 64 + ((ca    ) ^ m7) * 8);
        bf16x8 b1 = *(const bf16x8*)(Wsm + row * 64 + ((ca + 4) ^ m7) * 8);
#pragma unroll
        for (int mf = 0; mf < 3; mf++) {
            acc[mf][nf] = mfma16(af[mf][0], b0, acc[mf][nf]);
            acc[mf][nf] = mfma16(af[mf][1], b1, acc[mf][nf]);
        }
    }
    const int r0 = blockIdx.x * 192 + wave * 48;
#pragma unroll
    for (int mf = 0; mf < 3; mf++)
#pragma unroll
        for (int j = 0; j < 4; j++) {
            int r = r0 + mf * 16 + (lane >> 4) * 4 + j;
            int btq = r / 12, hh = r - btq * 12;
            int b = btq / 197, t = btq - b * 197;
            size_t dbase = ((size_t)(b * HH + hh) * TP + t) * 64;
#pragma unroll
            for (int nf = 0; nf < 12; nf++) {
                int col = nf * 16 + (lane & 15);
                float v = acc[mf][nf][j] + qb[col];
                int sel = nf >> 2, e = col & 63;
                bf16* dst = (sel == 0) ? Q : (sel == 1 ? Kb : Vb);
                dst[dbase + e] = (bf16)v;
            }
        }
}

// ---------------------------------------------------------------------------
// Fused attention: block = (b,h,half); 768 blocks. LDS 79.4 KB -> 2 blocks/CU.
// PV split into two k-halves reusing a per-wave 16x136 P buffer; P stored
// unnormalized, o scaled by 1/sum post-PV. (r9-proven)
// ---------------------------------------------------------------------------
__global__ __launch_bounds__(256, 2)
void attn_kernel(const bf16* __restrict__ Q, const bf16* __restrict__ Kg,
                 const bf16* __restrict__ Vg, float* __restrict__ h) {
    __shared__ bf16 Ks[TP * KST];
    __shared__ bf16 Vt[64 * PST];
    __shared__ bf16 Pw[4 * 16 * PST2];
    const int tid = threadIdx.x, lane = tid & 63, wave = tid >> 6;
    const int bh = blockIdx.x >> 1, sub = blockIdx.x & 1;
    const int b = bh / HH, hh = bh - b * HH;
    const bf16* Kp = Kg + (size_t)bh * TP * 64;
    const bf16* Vp = Vg + (size_t)bh * TP * 64;
    const bf16* Qp = Q + (size_t)bh * TP * 64;

#pragma unroll
    for (int i = 0; i < 7; i++) {
        int idx = i * 256 + tid;
        int row = idx >> 3, cb = idx & 7;
        bf16x8 kv = *(const bf16x8*)(Kp + idx * 8);
        *(bf16x8*)(Ks + row * KST + cb * 8) = kv;
        bf16x8 vv = *(const bf16x8*)(Vp + idx * 8);
#pragma unroll
        for (int j = 0; j < 8; j++) Vt[(cb * 8 + j) * PST + row] = vv[j];
    }
    __syncthreads();

    bf16* Pm = Pw + wave * 16 * PST2;
    const int cEnd = sub ? 13 : 7;
    for (int ch = sub * 7 + wave; ch < cEnd; ch += 4) {
        const int q0 = ch * 16;
        const bf16* qp = Qp + (q0 + (lane & 15)) * 64 + (lane >> 4) * 8;
        bf16x8 aq0 = *(const bf16x8*)qp;
        bf16x8 aq1 = *(const bf16x8*)(qp + 32);
        f32x4 s[14] = {};
#pragma unroll
        for (int nf = 0; nf < 14; nf++) {
            int rb = (nf * 16 + (lane & 15)) * KST + (lane >> 4) * 8;
            bf16x8 b0 = *(const bf16x8*)(Ks + rb);
            bf16x8 b1 = *(const bf16x8*)(Ks + rb + 32);
            s[nf] = mfma16(aq0, b0, s[nf]);
            s[nf] = mfma16(aq1, b1, s[nf]);
        }
        const int colbase = lane & 15;
        float mmax[4], minv[4];
#pragma unroll
        for (int j = 0; j < 4; j++) {
            float m = -1e30f;
#pragma unroll
            for (int nf = 0; nf < 14; nf++) {
                int col = nf * 16 + colbase;
                float v = (col < TT) ? s[nf][j] * 0.125f : -1e30f;
                m = fmaxf(m, v);
            }
#pragma unroll
            for (int dd = 1; dd < 16; dd <<= 1) m = fmaxf(m, __shfl_xor(m, dd));
            float sum = 0.0f;
#pragma unroll
            for (int nf = 0; nf < 14; nf++) {
                int col = nf * 16 + colbase;
                float v = (col < TT) ? s[nf][j] * 0.125f : -1e30f;
                sum += __expf(v - m);
            }
#pragma unroll
            for (int dd = 1; dd < 16; dd <<= 1) sum += __shfl_xor(sum, dd);
            mmax[j] = m;
            minv[j] = 1.0f / sum;
        }
        f32x4 o[4] = {};
#pragma unroll
        for (int j = 0; j < 4; j++) {
            int pr = (lane >> 4) * 4 + j;
#pragma unroll
            for (int nf = 0; nf < 8; nf++) {
                int col = nf * 16 + colbase;
                float v = (col < TT) ? s[nf][j] * 0.125f : -1e30f;
                Pm[pr * PST2 + nf * 16 + colbase] = (bf16)__expf(v - mmax[j]);
            }
        }
        asm volatile("s_waitcnt lgkmcnt(0)" ::: "memory");
#pragma unroll
        for (int ks = 0; ks < 4; ks++) {
            bf16x8 pa = *(const bf16x8*)(Pm + (lane & 15) * PST2 + ks * 32 + (lane >> 4) * 8);
#pragma unroll
            for (int nf = 0; nf < 4; nf++) {
                bf16x8 bv = *(const bf16x8*)(Vt + (nf * 16 + (lane & 15)) * PST + ks * 32 + (lane >> 4) * 8);
                o[nf] = mfma16(pa, bv, o[nf]);
            }
        }
        asm volatile("s_waitcnt lgkmcnt(0)" ::: "memory");
#pragma unroll
        for (int j = 0; j < 4; j++) {
            int pr = (lane >> 4) * 4 + j;
#pragma unroll
            for (int nf = 8; nf < 14; nf++) {
                int col = nf * 16 + colbase;
                float v = (col < TT) ? s[nf][j] * 0.125f : -1e30f;
                Pm[pr * PST2 + (nf - 8) * 16 + colbase] = (bf16)__expf(v - mmax[j]);
            }
        }
        asm volatile("s_waitcnt lgkmcnt(0)" ::: "memory");
#pragma unroll
        for (int ks = 4; ks < 7; ks++) {
            bf16x8 pa = *(const bf16x8*)(Pm + (lane & 15) * PST2 + (ks - 4) * 32 + (lane >> 4) * 8);
#pragma unroll
            for (int nf = 0; nf < 4; nf++) {
                bf16x8 bv = *(const bf16x8*)(Vt + (nf * 16 + (lane & 15)) * PST + ks * 32 + (lane >> 4) * 8);
                o[nf] = mfma16(pa, bv, o[nf]);
            }
        }
        asm volatile("s_waitcnt lgkmcnt(0)" ::: "memory");
#pragma unroll
        for (int nf = 0; nf < 4; nf++)
#pragma unroll
            for (int j = 0; j < 4; j++) {
                int qr = q0 + (lane >> 4) * 4 + j;
                if (qr < TT) {
                    int d = nf * 16 + (lane & 15);
                    h[(size_t)(b * TT + qr) * DD + hh * 64 + d] += o[nf][j] * minv[j];
                }
            }
    }
}

// ---------------------------------------------------------------------------
// LayerNorm (LN2 before MLP1), one row per wave, fp32 in -> bf16 out
// ---------------------------------------------------------------------------
__global__ void ln_kernel(const float* __restrict__ h, const float* __restrict__ g,
                          const float* __restrict__ bt, bf16* __restrict__ hn) {
    const int lane = threadIdx.x & 63, wave = threadIdx.x >> 6;
    const int row = blockIdx.x * 4 + wave;
    const float* x = h + (size_t)row * DD;
    float4 a[3];
#pragma unroll
    for (int i = 0; i < 3; i++) a[i] = ((const float4*)x)[lane + i * 64];
    float sum = 0.0f;
#pragma unroll
    for (int i = 0; i < 3; i++) sum += a[i].x + a[i].y + a[i].z + a[i].w;
#pragma unroll
    for (int dd = 1; dd < 64; dd <<= 1) sum += __shfl_xor(sum, dd);
    const float mu = sum * (1.0f / 768.0f);
    float sq = 0.0f;
#pragma unroll
    for (int i = 0; i < 3; i++) {
        float dx = a[i].x - mu, dy = a[i].y - mu, dz = a[i].z - mu, dw = a[i].w - mu;
        sq += dx * dx + dy * dy + dz * dz + dw * dw;
    }
#pragma unroll
    for (int dd = 1; dd < 64; dd <<= 1) sq += __shfl_xor(sq, dd);
    const float is = rsqrtf(sq * (1.0f / 768.0f) + 1e-5f);
#pragma unroll
    for (int i = 0; i < 3; i++) {
        int c4 = lane + i * 64;
        float4 gg = ((const float4*)g)[c4];
        float4 bb = ((const float4*)bt)[c4];
        bf16x4 o;
        o[0] = (bf16)((a[i].x - mu) * is * gg.x + bb.x);
        o[1] = (bf16)((a[i].y - mu) * is * gg.y + bb.y);
        o[2] = (bf16)((a[i].z - mu) * is * gg.z + bb.z);
        o[3] = (bf16)((a[i].w - mu) * is * gg.w + bb.w);
        ((bf16x4*)(hn + (size_t)row * DD))[c4] = o;
    }
}

// ---------------------------------------------------------------------------
__global__ void patch_extract(const float* __restrict__ x, bf16* __restrict__ p) {
    int idx = blockIdx.x * 256 + threadIdx.x;
    if (idx >= 6272 * 768) return;
    int k = idx % 768, row = idx / 768;
    int c = k % 3, pc = (k / 3) % 16, pr = k / 48;
    int b = row / 196, n = row - b * 196;
    int hp = n / 14, wp = n - hp * 14;
    p[idx] = (bf16)x[((size_t)(b * 3 + c) * 224 + hp * 16 + pr) * 224 + wp * 16 + pc];
}

// dual-range 8-wide cast: [0,n8a) -> oa, [n8a, n8a+n8b) -> ob.
__global__ void cast2w_bf16(const float* __restrict__ ia, bf16* __restrict__ oa,
                            const float* __restrict__ ib, bf16* __restrict__ ob,
                            int n8a, int n8b) {
    int i = blockIdx.x * 256 + threadIdx.x;
    int stride = gridDim.x * 256;
    for (; i < n8a + n8b; i += stride) {
        const float4* src = (i < n8a) ? (const float4*)ia + 2 * i
                                      : (const float4*)ib + 2 * (i - n8a);
        bf16x8* dst = (i < n8a) ? (bf16x8*)oa + i : (bf16x8*)ob + (i - n8a);
        float4 v0 = src[0];
        float4 v1 = src[1];
        bf16x8 o;
        o[0] = (bf16)v0.x; o[1] = (bf16)v0.y; o[2] = (bf16)v0.z; o[3] = (bf16)v0.w;
        o[4] = (bf16)v1.x; o[5] = (bf16)v1.y; o[6] = (bf16)v1.z; o[7] = (bf16)v1.w;
        *dst = o;
    }
}

__global__ void cls_init(const float* __restrict__ cls, const float* __restrict__ pos,
                         float* __restrict__ h) {
    int i = blockIdx.x * 256 + threadIdx.x;
    if (i >= BQ * DD) return;
    int b = i / DD, c = i - b * DD;
    h[(size_t)(b * TT) * DD + c] = cls[c] + pos[c];
}

// head over cls rows only; ACCP folds the final MLP2 bf16-partial reduce (+b2)
template <int ACCP>
__global__ void head_kernel(const float* __restrict__ h, const bf16* __restrict__ part,
                            const float* __restrict__ b2,
                            const float* __restrict__ hw, const float* __restrict__ hb,
                            float* __restrict__ out) {
    __shared__ float xr[DD];
    const int b = blockIdx.y;
    const int n = blockIdx.x * 256 + threadIdx.x;
    const size_t rowoff = (size_t)(b * TT) * DD;
    for (int i = threadIdx.x; i < DD; i += 256) {
        float v = h[rowoff + i];
        if (ACCP) {
            v += (float)part[((size_t)0 * MP + b * TT) * DD + i];
            v += (float)part[((size_t)1 * MP + b * TT) * DD + i];
            v += b2[i];
        }
        xr[i] = v;
    }
    __syncthreads();
    if (n < 1000) {
        float s = hb[n];
        const float4* w = (const float4*)(hw + (size_t)n * DD);
        float acc = 0.0f;
#pragma unroll 4
        for (int k = 0; k < DD / 4; k++) {
            float4 wv = w[k];
            float4 xv = ((const float4*)xr)[k];
            acc += wv.x * xv.x + wv.y * xv.y + wv.z * xv.z + wv.w * xv.w;
        }
        out[b * 1000 + n] = s + acc;
    }
}

// ---------------------------------------------------------------------------
extern "C" void kernel_launch(void* const* d_in, const int* in_sizes, int n_in,
                              void* d_out, int out_size, void* d_ws, size_t ws_size,
                              hipStream_t stream) {
    const float* x       = (const float*)d_in[0];
    const float* patch_w = (const float*)d_in[1];
    const float* patch_b = (const float*)d_in[2];
    const float* pos_enc = (const float*)d_in[3];
    const float* cls_tok = (const float*)d_in[4];
    const float* qkv_w   = (const float*)d_in[5];
    const float* qkv_b   = (const float*)d_in[6];
    const float* ln_g    = (const float*)d_in[7];
    const float* ln_b    = (const float*)d_in[8];
    const float* w1      = (const float*)d_in[9];
    const float* b1      = (const float*)d_in[10];
    const float* w2      = (const float*)d_in[11];
    const float* b2      = (const float*)d_in[12];
    const float* head_w  = (const float*)d_in[13];
    const float* head_b  = (const float*)d_in[14];

    char* wp = (char*)d_ws;
    auto carve = [&](size_t bytes) {
        char* r = wp;
        wp += (bytes + 255) & ~(size_t)255;
        return r;
    };
    auto fits = [&](size_t bytes) {
        return (size_t)(wp - (char*)d_ws) + bytes + 256 <= ws_size;
    };
    float* h  = (float*)carve((size_t)MP * DD * 4);
    bf16* hn  = (bf16*)carve((size_t)MP * DD * 2);
    bf16* u   = (bf16*)carve((size_t)MP * FF * 2);
    bf16* qs  = (bf16*)carve((size_t)BQ * HH * TP * 64 * 2);
    bf16* ks  = (bf16*)carve((size_t)BQ * HH * TP * 64 * 2);
    bf16* vs  = (bf16*)carve((size_t)BQ * HH * TP * 64 * 2);
    bf16* p   = (bf16*)carve((size_t)6272 * DD * 2);
    bf16* pwb = (bf16*)carve((size_t)DD * DD * 2);
    bf16* qwb = (bf16*)carve((size_t)LL * 192 * 64 * 2);

    // split-K partials (NSPLIT x MP x DD bf16), if ws allows
    bf16* part = nullptr;
    if (fits((size_t)NSPLIT * MP * DD * 2))
        part = (bf16*)carve((size_t)NSPLIT * MP * DD * 2);
    const bool use_part = (part != nullptr);

    cast2w_bf16<<<720, 256, 0, stream>>>(patch_w, pwb, qkv_w, qwb,
                                         (DD * DD) / 8, (LL * 192 * 64) / 8);
    patch_extract<<<18816, 256, 0, stream>>>(x, p);
    cls_init<<<96, 256, 0, stream>>>(cls_tok, pos_enc, h);
    gemm_bt<0, 1, 768, 768, 6, 49, 0><<<294, 256, 0, stream>>>(p, pwb, patch_b,
                                                               h, nullptr, pos_enc);

    for (int i = 0; i < LL; i++) {
        // fused LN1 (+ previous layer's MLP2 bf16-partial reduction) + QKV
        if (use_part && i > 0)
            lnqkv_kernel<1><<<MR / 16, 256, 0, stream>>>(h, part, b2 + (i - 1) * DD,
                                                         ln_g + i * DD, ln_b + i * DD,
                                                         qwb + i * 192 * 64, qkv_b + i * 192,
                                                         qs, ks, vs);
        else
            lnqkv_kernel<0><<<MR / 16, 256, 0, stream>>>(h, nullptr, nullptr,
                                                         ln_g + i * DD, ln_b + i * DD,
                                                         qwb + i * 192 * 64, qkv_b + i * 192,
                                                         qs, ks, vs);

        attn_kernel<<<BQ * HH * 2, 256, 0, stream>>>(qs, ks, vs, h);
        ln_kernel<<<MP / 4, 256, 0, stream>>>(h, ln_g + i * DD, ln_b + i * DD, hn);
        // MLP1: fp32 W staged+converted in-kernel (WF32=1)
        gemm_bt<1, 1, 768, 3072, 24, 50, 1><<<1200, 256, 0, stream>>>(
            hn, w1 + (size_t)i * FF * DD, b1 + i * FF, nullptr, u, nullptr);
        if (use_part)
            gemm_bt<3, NSPLIT, 3072, 768, 6, 50, 1><<<300 * NSPLIT, 256, 0, stream>>>(
                u, w2 + (size_t)i * FF * DD, nullptr, nullptr, part, nullptr);
        else
            gemm_bt<2, 1, 3072, 768, 6, 50, 1><<<300, 256, 0, stream>>>(
                u, w2 + (size_t)i * FF * DD, b2 + i * DD, h, nullptr, nullptr);
    }
    if (use_part)
        head_kernel<1><<<dim3(4, BQ), 256, 0, stream>>>(h, part, b2 + 11 * DD,
                                                        head_w, head_b, (float*)d_out);
    else
        head_kernel<0><<<dim3(4, BQ), 256, 0, stream>>>(h, nullptr, nullptr,
                                                        head_w, head_b, (float*)d_out);
}

// Round 14
// 1902.078 us; speedup vs baseline: 1.3348x; 1.3348x over previous
//
#include <hip/hip_runtime.h>
#include <hip/hip_bf16.h>
#include <math.h>

typedef __bf16 bf16;
typedef bf16 bf16x8 __attribute__((ext_vector_type(8)));
typedef bf16 bf16x4 __attribute__((ext_vector_type(4)));
typedef float f32x4 __attribute__((ext_vector_type(4)));

#define BQ 32
#define TT 197
#define DD 768
#define HH 12
#define FF 3072
#define LL 12
#define TP 224
#define MR 6304   // B*T
#define MP 6400   // padded to 50*128
#define KST 72    // K LDS row stride (elements)
#define PST 232   // Vt LDS row stride (elements)
#define PST2 136  // P half-buffer row stride (elements)
#define NSPLIT 2  // MLP2 split-K factor

typedef __attribute__((address_space(1))) const void gv_t;
typedef __attribute__((address_space(3))) void lv_t;

__device__ __forceinline__ void gld16(const void* g, void* l) {
    __builtin_amdgcn_global_load_lds((gv_t*)g, (lv_t*)l, 16, 0, 0);
}

__device__ __forceinline__ f32x4 mfma16(bf16x8 a, bf16x8 b, f32x4 c) {
    return __builtin_amdgcn_mfma_f32_16x16x32_bf16(a, b, c, 0, 0, 0);
}

// tanh-approx GELU via hw v_exp_f32; overflow-safe (e=inf -> th=1)
__device__ __forceinline__ float fast_gelu(float v) {
    float t = 0.79788456080286535588f * v * (1.0f + 0.044715f * v * v);
    float e = __expf(2.0f * t);
    float th = 1.0f - 2.0f / (e + 1.0f);
    return 0.5f * v * (1.0f + th);
}

// bijective XCD swizzle (m204): consecutive wgid stay on one XCD
__device__ __forceinline__ int xcd_swz(int bid, int nwg) {
    int q = nwg >> 3, r = nwg & 7;
    int xcd = bid & 7, pos = bid >> 3;
    int base = (xcd < r) ? xcd * (q + 1) : r * (q + 1) + (xcd - r) * q;
    return base + pos;
}

// ---------------------------------------------------------------------------
// C = A(M,K) @ W(N,K)^T GEMM, 128x128 tile, BK=64, 4 waves, single-buffered
// (m97 structure; r5-proven, r13's reg-staged variant REVERTED: async gld16
// B-staging is faster than reg-stage+ds_write — m151 confirmed on-device).
// XOR swizzle cb^(row&7) on global SOURCE (LDS dest linear), mirrored on the
// ds_read side -> 0 bank conflicts (PMC-verified r4/r5).
// EPI 0: +bias, patch-embed; EPI 1: +bias, GELU->bf16; EPI 2: +bias,
// residual +=; EPI 3: raw partial write (bf16, stride DD).
// ---------------------------------------------------------------------------
template <int EPI, int SPLITK, int KTOT, int NN, int GX, int GY>
__global__ __launch_bounds__(256, 4)
void gemm_bt(const bf16* __restrict__ A, const bf16* __restrict__ W,
             const float* __restrict__ bias,
             float* __restrict__ outF, bf16* __restrict__ outB,
             const float* __restrict__ pos) {
    __shared__ bf16 As[128 * 64];
    __shared__ bf16 Bs[128 * 64];
    const int tid = threadIdx.x;
    const int lane = tid & 63, wave = tid >> 6;
    const int wm = wave >> 1, wn = wave & 1;

    const int wgid = xcd_swz(blockIdx.x, GX * GY * SPLITK);
    const int ks   = (SPLITK > 1) ? wgid / (GX * GY) : 0;
    const int rem  = (SPLITK > 1) ? wgid % (GX * GY) : wgid;
    const int bx = rem % GX, by = rem / GX;
    const int m0 = by * 128, n0 = bx * 128;

    constexpr int kb = KTOT / SPLITK;
    constexpr int nt = kb / 64;
    const int k0 = ks * kb;

    f32x4 acc[4][4] = {};
    const bf16* Ab = A + (size_t)m0 * KTOT;
    const bf16* Wb = W + (size_t)n0 * KTOT;

#pragma unroll
    for (int t = 0; t < nt; ++t) {
        const int kt = k0 + t * 64;
#pragma unroll
        for (int i = 0; i < 4; i++) {
            int idx = i * 256 + tid;
            int row = idx >> 3, cb = idx & 7;
            int gcb = cb ^ (row & 7);   // pre-swizzled source column-block
            gld16(Ab + (size_t)row * KTOT + kt + gcb * 8, As + idx * 8);
            gld16(Wb + (size_t)row * KTOT + kt + gcb * 8, Bs + idx * 8);
        }
        __syncthreads();
        bf16x8 af[4][2], bfr[4][2];
        const int ca = lane >> 4;
#pragma unroll
        for (int f = 0; f < 4; f++) {
            int rowa = wm * 64 + f * 16 + (lane & 15);
            int ma = rowa & 7;
            af[f][0] = *(const bf16x8*)(As + rowa * 64 + ((ca    ) ^ ma) * 8);
            af[f][1] = *(const bf16x8*)(As + rowa * 64 + ((ca + 4) ^ ma) * 8);
            int rowb = wn * 64 + f * 16 + (lane & 15);
            int mb = rowb & 7;
            bfr[f][0] = *(const bf16x8*)(Bs + rowb * 64 + ((ca    ) ^ mb) * 8);
            bfr[f][1] = *(const bf16x8*)(Bs + rowb * 64 + ((ca + 4) ^ mb) * 8);
        }
#pragma unroll
        for (int kh = 0; kh < 2; kh++)
#pragma unroll
            for (int mf = 0; mf < 4; mf++)
#pragma unroll
                for (int nf = 0; nf < 4; nf++)
                    acc[mf][nf] = mfma16(af[mf][kh], bfr[nf][kh], acc[mf][nf]);
        __syncthreads();
    }

    const int r0 = m0 + wm * 64, c0 = n0 + wn * 64;
#pragma unroll
    for (int mf = 0; mf < 4; mf++) {
#pragma unroll
        for (int j = 0; j < 4; j++) {
            int row = r0 + mf * 16 + ((lane >> 4) * 4) + j;
            int pb = 0, pn = 0;
            if (EPI == 0) { pb = row / 196; pn = row - pb * 196; }
#pragma unroll
            for (int nf = 0; nf < 4; nf++) {
                int col = c0 + nf * 16 + (lane & 15);
                float v = acc[mf][nf][j];
                if (EPI == 0) {
                    v += bias[col];
                    float pv = pos[(size_t)(1 + pn) * DD + col];
                    outF[(size_t)(pb * TT + 1 + pn) * DD + col] = v + pv;
                } else if (EPI == 1) {
                    v += bias[col];
                    outB[(size_t)row * NN + col] = (bf16)fast_gelu(v);
                } else if (EPI == 2) {
                    v += bias[col];
                    if (row < MR) outF[(size_t)row * DD + col] += v;
                } else {
                    outB[(size_t)(ks * MP + row) * DD + col] = (bf16)v;
                }
            }
        }
    }
}

// ---------------------------------------------------------------------------
// Fused LN1 + QKV. Grid 394 blocks x 16 bt-rows. Phase 1: (optional) bf16
// partial reduce + b2 + residual -> h, LN -> swizzled 192x64 bf16 A-tile in
// LDS. Phase 2: (192x192x64) MFMA vs qkv_w, scatter to Q/K/V (B*H, 224, 64).
// W staged via gld16 BEFORE phase 1 (latency hidden).
// ---------------------------------------------------------------------------
template <int ACC>
__global__ __launch_bounds__(256, 2)
void lnqkv_kernel(float* __restrict__ h, const bf16* __restrict__ part,
                  const float* __restrict__ b2p,
                  const float* __restrict__ g, const float* __restrict__ bt,
                  const bf16* __restrict__ qw, const float* __restrict__ qb,
                  bf16* __restrict__ Q, bf16* __restrict__ Kb,
                  bf16* __restrict__ Vb) {
    __shared__ bf16 Asm[192 * 64];
    __shared__ bf16 Wsm[192 * 64];
    const int tid = threadIdx.x, lane = tid & 63, wave = tid >> 6;
    const int g0 = blockIdx.x * 16;

    // stage W early; drains at the __syncthreads below
#pragma unroll
    for (int i = 0; i < 6; i++) {
        int idx = i * 256 + tid;
        int row = idx >> 3, cb = idx & 7;
        int gcb = cb ^ (row & 7);
        gld16(qw + (size_t)row * 64 + gcb * 8, Wsm + idx * 8);
    }

    // phase 1: 4 rows per wave; residual+LN -> Asm (swizzled col-blocks)
    for (int r = 0; r < 4; r++) {
        const int row = g0 + wave * 4 + r;
        float* x = h + (size_t)row * DD;
        float4 a[3];
#pragma unroll
        for (int i = 0; i < 3; i++) a[i] = ((const float4*)x)[lane + i * 64];
        if (ACC) {
#pragma unroll
            for (int s = 0; s < NSPLIT; s++) {
                const bf16x4* ps = (const bf16x4*)(part + ((size_t)s * MP + row) * DD);
#pragma unroll
                for (int i = 0; i < 3; i++) {
                    bf16x4 p = ps[lane + i * 64];
                    a[i].x += (float)p[0]; a[i].y += (float)p[1];
                    a[i].z += (float)p[2]; a[i].w += (float)p[3];
                }
            }
#pragma unroll
            for (int i = 0; i < 3; i++) {
                float4 bb = ((const float4*)b2p)[lane + i * 64];
                a[i].x += bb.x; a[i].y += bb.y; a[i].z += bb.z; a[i].w += bb.w;
                ((float4*)x)[lane + i * 64] = a[i];
            }
        }
        float sum = 0.0f;
#pragma unroll
        for (int i = 0; i < 3; i++) sum += a[i].x + a[i].y + a[i].z + a[i].w;
#pragma unroll
        for (int dd = 1; dd < 64; dd <<= 1) sum += __shfl_xor(sum, dd);
        const float mu = sum * (1.0f / 768.0f);
        float sq = 0.0f;
#pragma unroll
        for (int i = 0; i < 3; i++) {
            float dx = a[i].x - mu, dy = a[i].y - mu, dz = a[i].z - mu, dw = a[i].w - mu;
            sq += dx * dx + dy * dy + dz * dz + dw * dw;
        }
#pragma unroll
        for (int dd = 1; dd < 64; dd <<= 1) sq += __shfl_xor(sq, dd);
        const float is = rsqrtf(sq * (1.0f / 768.0f) + 1e-5f);
#pragma unroll
        for (int i = 0; i < 3; i++) {
            int c4 = lane + i * 64;
            float4 gg = ((const float4*)g)[c4];
            float4 bb = ((const float4*)bt)[c4];
            bf16x4 o;
            o[0] = (bf16)((a[i].x - mu) * is * gg.x + bb.x);
            o[1] = (bf16)((a[i].y - mu) * is * gg.y + bb.y);
            o[2] = (bf16)((a[i].z - mu) * is * gg.z + bb.z);
            o[3] = (bf16)((a[i].w - mu) * is * gg.w + bb.w);
            int col = c4 * 4;
            int arow = (row - g0) * 12 + (col >> 6);
            int acol = col & 63;
            int scol = (((acol >> 3) ^ (arow & 7)) << 3) + (acol & 7);
            *(bf16x4*)(Asm + arow * 64 + scol) = o;
        }
    }
    __syncthreads();   // drains W gld16 (vmcnt) + Asm writes (lgkm)

    // phase 2: QKV MFMA, 3 m-frags x 12 n-frags per wave
    const int ca = lane >> 4;
    bf16x8 af[3][2];
#pragma unroll
    for (int mf = 0; mf < 3; mf++) {
        int row = wave * 48 + mf * 16 + (lane & 15);
        int m7 = row & 7;
        af[mf][0] = *(const bf16x8*)(Asm + row * 64 + ((ca    ) ^ m7) * 8);
        af[mf][1] = *(const bf16x8*)(Asm + row * 64 + ((ca + 4) ^ m7) * 8);
    }
    f32x4 acc[3][12] = {};
#pragma unroll
    for (int nf = 0; nf < 12; nf++) {
        int row = nf * 16 + (lane & 15);
        int m7 = row & 7;
        bf16x8 b0 = *(const bf16x8*)(Wsm + row * 64 + ((ca    ) ^ m7) * 8);
        bf16x8 b1 = *(const bf16x8*)(Wsm + row * 64 + ((ca + 4) ^ m7) * 8);
#pragma unroll
        for (int mf = 0; mf < 3; mf++) {
            acc[mf][nf] = mfma16(af[mf][0], b0, acc[mf][nf]);
            acc[mf][nf] = mfma16(af[mf][1], b1, acc[mf][nf]);
        }
    }
    const int r0 = blockIdx.x * 192 + wave * 48;
#pragma unroll
    for (int mf = 0; mf < 3; mf++)
#pragma unroll
        for (int j = 0; j < 4; j++) {
            int r = r0 + mf * 16 + (lane >> 4) * 4 + j;
            int btq = r / 12, hh = r - btq * 12;
            int b = btq / 197, t = btq - b * 197;
            size_t dbase = ((size_t)(b * HH + hh) * TP + t) * 64;
#pragma unroll
            for (int nf = 0; nf < 12; nf++) {
                int col = nf * 16 + (lane & 15);
                float v = acc[mf][nf][j] + qb[col];
                int sel = nf >> 2, e = col & 63;
                bf16* dst = (sel == 0) ? Q : (sel == 1 ? Kb : Vb);
                dst[dbase + e] = (bf16)v;
            }
        }
}

// ---------------------------------------------------------------------------
// Fused attention: block = (b,h,half); 768 blocks. LDS 79.4 KB -> 2 blocks/CU.
// PV split into two k-halves reusing a per-wave 16x136 P buffer; P stored
// unnormalized, o scaled by 1/sum post-PV. (r9-proven)
// ---------------------------------------------------------------------------
__global__ __launch_bounds__(256, 2)
void attn_kernel(const bf16* __restrict__ Q, const bf16* __restrict__ Kg,
                 const bf16* __restrict__ Vg, float* __restrict__ h) {
    __shared__ bf16 Ks[TP * KST];
    __shared__ bf16 Vt[64 * PST];
    __shared__ bf16 Pw[4 * 16 * PST2];
    const int tid = threadIdx.x, lane = tid & 63, wave = tid >> 6;
    const int bh = blockIdx.x >> 1, sub = blockIdx.x & 1;
    const int b = bh / HH, hh = bh - b * HH;
    const bf16* Kp = Kg + (size_t)bh * TP * 64;
    const bf16* Vp = Vg + (size_t)bh * TP * 64;
    const bf16* Qp = Q + (size_t)bh * TP * 64;

#pragma unroll
    for (int i = 0; i < 7; i++) {
        int idx = i * 256 + tid;
        int row = idx >> 3, cb = idx & 7;
        bf16x8 kv = *(const bf16x8*)(Kp + idx * 8);
        *(bf16x8*)(Ks + row * KST + cb * 8) = kv;
        bf16x8 vv = *(const bf16x8*)(Vp + idx * 8);
#pragma unroll
        for (int j = 0; j < 8; j++) Vt[(cb * 8 + j) * PST + row] = vv[j];
    }
    __syncthreads();

    bf16* Pm = Pw + wave * 16 * PST2;
    const int cEnd = sub ? 13 : 7;
    for (int ch = sub * 7 + wave; ch < cEnd; ch += 4) {
        const int q0 = ch * 16;
        const bf16* qp = Qp + (q0 + (lane & 15)) * 64 + (lane >> 4) * 8;
        bf16x8 aq0 = *(const bf16x8*)qp;
        bf16x8 aq1 = *(const bf16x8*)(qp + 32);
        f32x4 s[14] = {};
#pragma unroll
        for (int nf = 0; nf < 14; nf++) {
            int rb = (nf * 16 + (lane & 15)) * KST + (lane >> 4) * 8;
            bf16x8 b0 = *(const bf16x8*)(Ks + rb);
            bf16x8 b1 = *(const bf16x8*)(Ks + rb + 32);
            s[nf] = mfma16(aq0, b0, s[nf]);
            s[nf] = mfma16(aq1, b1, s[nf]);
        }
        const int colbase = lane & 15;
        float mmax[4], minv[4];
#pragma unroll
        for (int j = 0; j < 4; j++) {
            float m = -1e30f;
#pragma unroll
            for (int nf = 0; nf < 14; nf++) {
                int col = nf * 16 + colbase;
                float v = (col < TT) ? s[nf][j] * 0.125f : -1e30f;
                m = fmaxf(m, v);
            }
#pragma unroll
            for (int dd = 1; dd < 16; dd <<= 1) m = fmaxf(m, __shfl_xor(m, dd));
            float sum = 0.0f;
#pragma unroll
            for (int nf = 0; nf < 14; nf++) {
                int col = nf * 16 + colbase;
                float v = (col < TT) ? s[nf][j] * 0.125f : -1e30f;
                sum += __expf(v - m);
            }
#pragma unroll
            for (int dd = 1; dd < 16; dd <<= 1) sum += __shfl_xor(sum, dd);
            mmax[j] = m;
            minv[j] = 1.0f / sum;
        }
        f32x4 o[4] = {};
#pragma unroll
        for (int j = 0; j < 4; j++) {
            int pr = (lane >> 4) * 4 + j;
#pragma unroll
            for (int nf = 0; nf < 8; nf++) {
                int col = nf * 16 + colbase;
                float v = (col < TT) ? s[nf][j] * 0.125f : -1e30f;
                Pm[pr * PST2 + nf * 16 + colbase] = (bf16)__expf(v - mmax[j]);
            }
        }
        asm volatile("s_waitcnt lgkmcnt(0)" ::: "memory");
#pragma unroll
        for (int ks = 0; ks < 4; ks++) {
            bf16x8 pa = *(const bf16x8*)(Pm + (lane & 15) * PST2 + ks * 32 + (lane >> 4) * 8);
#pragma unroll
            for (int nf = 0; nf < 4; nf++) {
                bf16x8 bv = *(const bf16x8*)(Vt + (nf * 16 + (lane & 15)) * PST + ks * 32 + (lane >> 4) * 8);
                o[nf] = mfma16(pa, bv, o[nf]);
            }
        }
        asm volatile("s_waitcnt lgkmcnt(0)" ::: "memory");
#pragma unroll
        for (int j = 0; j < 4; j++) {
            int pr = (lane >> 4) * 4 + j;
#pragma unroll
            for (int nf = 8; nf < 14; nf++) {
                int col = nf * 16 + colbase;
                float v = (col < TT) ? s[nf][j] * 0.125f : -1e30f;
                Pm[pr * PST2 + (nf - 8) * 16 + colbase] = (bf16)__expf(v - mmax[j]);
            }
        }
        asm volatile("s_waitcnt lgkmcnt(0)" ::: "memory");
#pragma unroll
        for (int ks = 4; ks < 7; ks++) {
            bf16x8 pa = *(const bf16x8*)(Pm + (lane & 15) * PST2 + (ks - 4) * 32 + (lane >> 4) * 8);
#pragma unroll
            for (int nf = 0; nf < 4; nf++) {
                bf16x8 bv = *(const bf16x8*)(Vt + (nf * 16 + (lane & 15)) * PST + ks * 32 + (lane >> 4) * 8);
                o[nf] = mfma16(pa, bv, o[nf]);
            }
        }
        asm volatile("s_waitcnt lgkmcnt(0)" ::: "memory");
#pragma unroll
        for (int nf = 0; nf < 4; nf++)
#pragma unroll
            for (int j = 0; j < 4; j++) {
                int qr = q0 + (lane >> 4) * 4 + j;
                if (qr < TT) {
                    int d = nf * 16 + (lane & 15);
                    h[(size_t)(b * TT + qr) * DD + hh * 64 + d] += o[nf][j] * minv[j];
                }
            }
    }
}

// ---------------------------------------------------------------------------
// LayerNorm (LN2 before MLP1), one row per wave, fp32 in -> bf16 out
// ---------------------------------------------------------------------------
__global__ void ln_kernel(const float* __restrict__ h, const float* __restrict__ g,
                          const float* __restrict__ bt, bf16* __restrict__ hn) {
    const int lane = threadIdx.x & 63, wave = threadIdx.x >> 6;
    const int row = blockIdx.x * 4 + wave;
    const float* x = h + (size_t)row * DD;
    float4 a[3];
#pragma unroll
    for (int i = 0; i < 3; i++) a[i] = ((const float4*)x)[lane + i * 64];
    float sum = 0.0f;
#pragma unroll
    for (int i = 0; i < 3; i++) sum += a[i].x + a[i].y + a[i].z + a[i].w;
#pragma unroll
    for (int dd = 1; dd < 64; dd <<= 1) sum += __shfl_xor(sum, dd);
    const float mu = sum * (1.0f / 768.0f);
    float sq = 0.0f;
#pragma unroll
    for (int i = 0; i < 3; i++) {
        float dx = a[i].x - mu, dy = a[i].y - mu, dz = a[i].z - mu, dw = a[i].w - mu;
        sq += dx * dx + dy * dy + dz * dz + dw * dw;
    }
#pragma unroll
    for (int dd = 1; dd < 64; dd <<= 1) sq += __shfl_xor(sq, dd);
    const float is = rsqrtf(sq * (1.0f / 768.0f) + 1e-5f);
#pragma unroll
    for (int i = 0; i < 3; i++) {
        int c4 = lane + i * 64;
        float4 gg = ((const float4*)g)[c4];
        float4 bb = ((const float4*)bt)[c4];
        bf16x4 o;
        o[0] = (bf16)((a[i].x - mu) * is * gg.x + bb.x);
        o[1] = (bf16)((a[i].y - mu) * is * gg.y + bb.y);
        o[2] = (bf16)((a[i].z - mu) * is * gg.z + bb.z);
        o[3] = (bf16)((a[i].w - mu) * is * gg.w + bb.w);
        ((bf16x4*)(hn + (size_t)row * DD))[c4] = o;
    }
}

// ---------------------------------------------------------------------------
// patch extract + cls init merged (disjoint block ranges, one launch)
__global__ void patchcls_kernel(const float* __restrict__ x, bf16* __restrict__ p,
                                const float* __restrict__ cls,
                                const float* __restrict__ pos, float* __restrict__ h) {
    if (blockIdx.x < 18816) {
        int idx = blockIdx.x * 256 + threadIdx.x;
        if (idx >= 6272 * 768) return;
        int k = idx % 768, row = idx / 768;
        int c = k % 3, pc = (k / 3) % 16, pr = k / 48;
        int b = row / 196, n = row - b * 196;
        int hp = n / 14, wp = n - hp * 14;
        p[idx] = (bf16)x[((size_t)(b * 3 + c) * 224 + hp * 16 + pr) * 224 + wp * 16 + pc];
    } else {
        int i = (blockIdx.x - 18816) * 256 + threadIdx.x;
        if (i >= BQ * DD) return;
        int b = i / DD, c = i - b * DD;
        h[(size_t)(b * TT) * DD + c] = cls[c] + pos[c];
    }
}

// dual-range 8-wide cast: [0,n8a) -> oa, [n8a, n8a+n8b) -> ob.
__global__ void cast2w_bf16(const float* __restrict__ ia, bf16* __restrict__ oa,
                            const float* __restrict__ ib, bf16* __restrict__ ob,
                            int n8a, int n8b) {
    int i = blockIdx.x * 256 + threadIdx.x;
    int stride = gridDim.x * 256;
    for (; i < n8a + n8b; i += stride) {
        const float4* src = (i < n8a) ? (const float4*)ia + 2 * i
                                      : (const float4*)ib + 2 * (i - n8a);
        bf16x8* dst = (i < n8a) ? (bf16x8*)oa + i : (bf16x8*)ob + (i - n8a);
        float4 v0 = src[0];
        float4 v1 = src[1];
        bf16x8 o;
        o[0] = (bf16)v0.x; o[1] = (bf16)v0.y; o[2] = (bf16)v0.z; o[3] = (bf16)v0.w;
        o[4] = (bf16)v1.x; o[5] = (bf16)v1.y; o[6] = (bf16)v1.z; o[7] = (bf16)v1.w;
        *dst = o;
    }
}

__global__ void cast_bf16(const float* __restrict__ in, bf16* __restrict__ out, int n4) {
    int i = blockIdx.x * 256 + threadIdx.x;
    int stride = gridDim.x * 256;
    for (; i < n4; i += stride) {
        float4 v = ((const float4*)in)[i];
        bf16x4 o;
        o[0] = (bf16)v.x; o[1] = (bf16)v.y; o[2] = (bf16)v.z; o[3] = (bf16)v.w;
        ((bf16x4*)out)[i] = o;
    }
}

// head over cls rows only; ACCP folds the final MLP2 bf16-partial reduce (+b2)
template <int ACCP>
__global__ void head_kernel(const float* __restrict__ h, const bf16* __restrict__ part,
                            const float* __restrict__ b2,
                            const float* __restrict__ hw, const float* __restrict__ hb,
                            float* __restrict__ out) {
    __shared__ float xr[DD];
    const int b = blockIdx.y;
    const int n = blockIdx.x * 256 + threadIdx.x;
    const size_t rowoff = (size_t)(b * TT) * DD;
    for (int i = threadIdx.x; i < DD; i += 256) {
        float v = h[rowoff + i];
        if (ACCP) {
            v += (float)part[((size_t)0 * MP + b * TT) * DD + i];
            v += (float)part[((size_t)1 * MP + b * TT) * DD + i];
            v += b2[i];
        }
        xr[i] = v;
    }
    __syncthreads();
    if (n < 1000) {
        float s = hb[n];
        const float4* w = (const float4*)(hw + (size_t)n * DD);
        float acc = 0.0f;
#pragma unroll 4
        for (int k = 0; k < DD / 4; k++) {
            float4 wv = w[k];
            float4 xv = ((const float4*)xr)[k];
            acc += wv.x * xv.x + wv.y * xv.y + wv.z * xv.z + wv.w * xv.w;
        }
        out[b * 1000 + n] = s + acc;
    }
}

// ---------------------------------------------------------------------------
extern "C" void kernel_launch(void* const* d_in, const int* in_sizes, int n_in,
                              void* d_out, int out_size, void* d_ws, size_t ws_size,
                              hipStream_t stream) {
    const float* x       = (const float*)d_in[0];
    const float* patch_w = (const float*)d_in[1];
    const float* patch_b = (const float*)d_in[2];
    const float* pos_enc = (const float*)d_in[3];
    const float* cls_tok = (const float*)d_in[4];
    const float* qkv_w   = (const float*)d_in[5];
    const float* qkv_b   = (const float*)d_in[6];
    const float* ln_g    = (const float*)d_in[7];
    const float* ln_b    = (const float*)d_in[8];
    const float* w1      = (const float*)d_in[9];
    const float* b1      = (const float*)d_in[10];
    const float* w2      = (const float*)d_in[11];
    const float* b2      = (const float*)d_in[12];
    const float* head_w  = (const float*)d_in[13];
    const float* head_b  = (const float*)d_in[14];

    char* wp = (char*)d_ws;
    auto carve = [&](size_t bytes) {
        char* r = wp;
        wp += (bytes + 255) & ~(size_t)255;
        return r;
    };
    auto fits = [&](size_t bytes) {
        return (size_t)(wp - (char*)d_ws) + bytes + 256 <= ws_size;
    };
    float* h  = (float*)carve((size_t)MP * DD * 4);
    bf16* hn  = (bf16*)carve((size_t)MP * DD * 2);
    bf16* u   = (bf16*)carve((size_t)MP * FF * 2);
    bf16* qs  = (bf16*)carve((size_t)BQ * HH * TP * 64 * 2);
    bf16* ks  = (bf16*)carve((size_t)BQ * HH * TP * 64 * 2);
    bf16* vs  = (bf16*)carve((size_t)BQ * HH * TP * 64 * 2);
    bf16* p   = (bf16*)carve((size_t)6272 * DD * 2);
    bf16* pwb = (bf16*)carve((size_t)DD * DD * 2);
    bf16* qwb = (bf16*)carve((size_t)LL * 192 * 64 * 2);

    // split-K partials (NSPLIT x MP x DD bf16), if ws allows
    bf16* part = nullptr;
    if (fits((size_t)NSPLIT * MP * DD * 2))
        part = (bf16*)carve((size_t)NSPLIT * MP * DD * 2);
    const bool use_part = (part != nullptr);

    // precast-all weights, if ws allows
    const size_t wfull = (size_t)LL * FF * DD * 2;
    const bool precast = fits(2 * (wfull + 256));
    bf16* w1b = (bf16*)carve(precast ? wfull : (size_t)FF * DD * 2);
    bf16* w2b = (bf16*)carve(precast ? wfull : (size_t)DD * FF * 2);

    cast2w_bf16<<<720, 256, 0, stream>>>(patch_w, pwb, qkv_w, qwb,
                                         (DD * DD) / 8, (LL * 192 * 64) / 8);
    if (precast) {
        cast2w_bf16<<<8192, 256, 0, stream>>>(w1, w1b, w2, w2b,
                                              (LL * FF * DD) / 8, (LL * FF * DD) / 8);
    }
    patchcls_kernel<<<18816 + 96, 256, 0, stream>>>(x, p, cls_tok, pos_enc, h);
    gemm_bt<0, 1, 768, 768, 6, 49><<<294, 256, 0, stream>>>(p, pwb, patch_b,
                                                            h, nullptr, pos_enc);

    for (int i = 0; i < LL; i++) {
        const bf16* w1i = precast ? (w1b + (size_t)i * FF * DD) : w1b;
        const bf16* w2i = precast ? (w2b + (size_t)i * FF * DD) : w2b;

        // fused LN1 (+ previous layer's MLP2 bf16-partial reduction) + QKV
        if (use_part && i > 0)
            lnqkv_kernel<1><<<MR / 16, 256, 0, stream>>>(h, part, b2 + (i - 1) * DD,
                                                         ln_g + i * DD, ln_b + i * DD,
                                                         qwb + i * 192 * 64, qkv_b + i * 192,
                                                         qs, ks, vs);
        else
            lnqkv_kernel<0><<<MR / 16, 256, 0, stream>>>(h, nullptr, nullptr,
                                                         ln_g + i * DD, ln_b + i * DD,
                                                         qwb + i * 192 * 64, qkv_b + i * 192,
                                                         qs, ks, vs);

        attn_kernel<<<BQ * HH * 2, 256, 0, stream>>>(qs, ks, vs, h);
        ln_kernel<<<MP / 4, 256, 0, stream>>>(h, ln_g + i * DD, ln_b + i * DD, hn);
        if (!precast)
            cast_bf16<<<2048, 256, 0, stream>>>(w1 + (size_t)i * FF * DD, w1b, (FF * DD) / 4);
        gemm_bt<1, 1, 768, 3072, 24, 50><<<1200, 256, 0, stream>>>(hn, w1i, b1 + i * FF,
                                                                   nullptr, u, nullptr);
        if (!precast)
            cast_bf16<<<2048, 256, 0, stream>>>(w2 + (size_t)i * FF * DD, w2b, (FF * DD) / 4);
        if (use_part)
            gemm_bt<3, NSPLIT, 3072, 768, 6, 50><<<300 * NSPLIT, 256, 0, stream>>>(
                u, w2i, nullptr, nullptr, part, nullptr);
        else
            gemm_bt<2, 1, 3072, 768, 6, 50><<<300, 256, 0, stream>>>(
                u, w2i, b2 + i * DD, h, nullptr, nullptr);
    }
    if (use_part)
        head_kernel<1><<<dim3(4, BQ), 256, 0, stream>>>(h, part, b2 + 11 * DD,
                                                        head_w, head_b, (float*)d_out);
    else
        head_kernel<0><<<dim3(4, BQ), 256, 0, stream>>>(h, nullptr, nullptr,
                                                        head_w, head_b, (float*)d_out);
}